// Round 1
// baseline (570.943 us; speedup 1.0000x reference)
//
#include <hip/hip_runtime.h>

typedef _Float16 f16x8 __attribute__((ext_vector_type(8)));
typedef _Float16 f16x4 __attribute__((ext_vector_type(4)));
typedef float f32x4 __attribute__((ext_vector_type(4)));

#define NB_   8
#define NN_   2000
#define TT_   64
#define FF_   32
#define HH_   128
#define EE_   32000
#define KD    160   // F + H
#define KP    168   // padded LDS row (fp16 elems): 336 B, 16B-aligned frags, 2-way-bank-free
#define NODES 64

__device__ __forceinline__ float fsigmoid(float v) {
  return __builtin_amdgcn_rcpf(1.f + __builtin_amdgcn_exp2f(-1.44269504f * v));
}
__device__ __forceinline__ float ftanh(float v) {
  return 1.f - 2.f * __builtin_amdgcn_rcpf(1.f + __builtin_amdgcn_exp2f(2.88539008f * v));
}

// ---- prep: pack [Wih|Whh] -> fp16 [512][160], gcn_W^T -> fp16 [128][128], bias=bih+bhh
__global__ void prep_kernel(const float* __restrict__ Wih, const float* __restrict__ Whh,
                            const float* __restrict__ bih, const float* __restrict__ bhh,
                            const float* __restrict__ gcnW,
                            _Float16* __restrict__ W16, _Float16* __restrict__ Wg16,
                            float* __restrict__ bias) {
  int idx = blockIdx.x * 256 + threadIdx.x;
  if (idx < 512 * KD) {
    int col = idx / KD, k = idx % KD;
    float v = (k < 32) ? Wih[col * 32 + k] : Whh[col * 128 + (k - 32)];
    W16[idx] = (_Float16)v;
  } else if (idx < 512 * KD + 128 * 128) {
    int i2 = idx - 512 * KD;
    int colg = i2 >> 7, k = i2 & 127;
    Wg16[i2] = (_Float16)gcnW[k * 128 + colg];   // Wg16[c][k] = gcnW[k][c]
  } else if (idx < 512 * KD + 128 * 128 + 512) {
    int i3 = idx - (512 * KD + 128 * 128);
    bias[i3] = bih[i3] + bhh[i3];
  }
}

// ---- agg = gcn_b broadcast, deg = 0
__global__ void init_kernel(float* __restrict__ agg, float* __restrict__ deg,
                            const float* __restrict__ gcnb) {
  int idx = blockIdx.x * 256 + threadIdx.x;
  if (idx < 16000 * 128) agg[idx] = gcnb[idx & 127];
  if (idx < NN_) deg[idx] = 0.f;
}

__global__ void deg_kernel(const int* __restrict__ ei, float* __restrict__ deg) {
  int e = blockIdx.x * 256 + threadIdx.x;
  if (e < EE_ + NN_) {
    int d = (e < EE_) ? ei[EE_ + e] : (e - EE_);
    atomicAdd(&deg[d], 1.f);
  }
}

__global__ void dinv_kernel(const float* __restrict__ deg, float* __restrict__ dinv) {
  int n = blockIdx.x * 256 + threadIdx.x;
  if (n < NN_) {
    float d = deg[n];
    dinv[n] = (d > 0.f) ? __builtin_amdgcn_rsqf(d) : 0.f;
  }
}

// ---- fused LSTM (T=64 recurrence) + GCN xw GEMM epilogue
// 250 blocks x 512 thr. Each block: 64 nodes. Wave w owns h-indices [16w,16w+16).
// A_lds[m][0:32]=x_t fp16, [32:160]=h_t fp16. LSTM weights persist in VGPRs.
__global__ __launch_bounds__(512, 2) void lstm_gcn_kernel(
    const float* __restrict__ x, const _Float16* __restrict__ W16,
    const float* __restrict__ bias, const _Float16* __restrict__ Wg16,
    float* __restrict__ xw) {
  __shared__ _Float16 A[NODES * KP];   // 21504 B
  const int tid  = threadIdx.x;
  const int wave = tid >> 6;
  const int lane = tid & 63;
  const int n15  = lane & 15;
  const int q    = lane >> 4;
  const int node0 = blockIdx.x * NODES;

  // B-fragments: B[k][n] = W16[col=n][k]; lane reads 8 contiguous k of row n15's col
  f16x8 Bf[4][5];
  float bg[4];
#pragma unroll
  for (int g = 0; g < 4; ++g) {
    const int col = g * 128 + wave * 16 + n15;
#pragma unroll
    for (int kc = 0; kc < 5; ++kc)
      Bf[g][kc] = *(const f16x8*)(W16 + col * KD + kc * 32 + q * 8);
    bg[g] = bias[col];
  }

  // h0 = 0
  for (int i = tid; i < NODES * HH_; i += 512)
    A[(i >> 7) * KP + 32 + (i & 127)] = (_Float16)0.f;

  // x0 load: 64 nodes x 32 f = 512 float4s, one per thread
  const int xnode = tid >> 3;
  const int xf    = (tid & 7) * 4;
  const float* xptr = x + (size_t)(node0 + xnode) * (TT_ * FF_) + xf;
  {
    float4 xv = *(const float4*)xptr;
    f16x4 t4 = { (_Float16)xv.x, (_Float16)xv.y, (_Float16)xv.z, (_Float16)xv.w };
    *(f16x4*)(&A[xnode * KP + xf]) = t4;
  }
  __syncthreads();

  f32x4 c[4];
#pragma unroll
  for (int mt = 0; mt < 4; ++mt) c[mt] = (f32x4){0.f, 0.f, 0.f, 0.f};

  for (int t = 0; t < TT_; ++t) {
    f32x4 acc[4][4];
#pragma unroll
    for (int mt = 0; mt < 4; ++mt)
#pragma unroll
      for (int g = 0; g < 4; ++g)
        acc[mt][g] = (f32x4){bg[g], bg[g], bg[g], bg[g]};

#pragma unroll
    for (int kc = 0; kc < 5; ++kc) {
      f16x8 af[4];
#pragma unroll
      for (int mt = 0; mt < 4; ++mt)
        af[mt] = *(const f16x8*)(&A[(mt * 16 + n15) * KP + kc * 32 + q * 8]);
#pragma unroll
      for (int mt = 0; mt < 4; ++mt)
#pragma unroll
        for (int g = 0; g < 4; ++g)
          acc[mt][g] = __builtin_amdgcn_mfma_f32_16x16x32_f16(af[mt], Bf[g][kc], acc[mt][g], 0, 0, 0);
    }

    const bool last = (t == TT_ - 1);
    float4 xnext;
    if (!last) xnext = *(const float4*)(xptr + (t + 1) * FF_);

    __syncthreads();   // all A-reads (MFMA) done before h/x writes

    // gates: C-layout col=lane&15 (h-idx), row=q*4+r (node in M-tile)
#pragma unroll
    for (int mt = 0; mt < 4; ++mt) {
#pragma unroll
      for (int r = 0; r < 4; ++r) {
        float ig = fsigmoid(acc[mt][0][r]);
        float fg = fsigmoid(acc[mt][1][r]);
        float gg = ftanh(acc[mt][2][r]);
        float og = fsigmoid(acc[mt][3][r]);
        float cn = fg * c[mt][r] + ig * gg;
        c[mt][r] = cn;
        float hn = og * ftanh(cn);
        int node = mt * 16 + q * 4 + r;
        A[node * KP + 32 + wave * 16 + n15] = (_Float16)hn;
      }
    }
    if (!last) {
      f16x4 t4 = { (_Float16)xnext.x, (_Float16)xnext.y, (_Float16)xnext.z, (_Float16)xnext.w };
      *(f16x4*)(&A[xnode * KP + xf]) = t4;
    }
    __syncthreads();
  }

  // epilogue: xw = h_T @ gcn_W (h_T already in LDS in A-layout). Wave owns 16 cols.
  f16x8 Bg[4];
#pragma unroll
  for (int kc = 0; kc < 4; ++kc)
    Bg[kc] = *(const f16x8*)(Wg16 + (wave * 16 + n15) * HH_ + kc * 32 + q * 8);
  f32x4 acc2[4];
#pragma unroll
  for (int mt = 0; mt < 4; ++mt) acc2[mt] = (f32x4){0.f, 0.f, 0.f, 0.f};
#pragma unroll
  for (int kc = 0; kc < 4; ++kc)
#pragma unroll
    for (int mt = 0; mt < 4; ++mt) {
      f16x8 af = *(const f16x8*)(&A[(mt * 16 + n15) * KP + 32 + kc * 32 + q * 8]);
      acc2[mt] = __builtin_amdgcn_mfma_f32_16x16x32_f16(af, Bg[kc], acc2[mt], 0, 0, 0);
    }
#pragma unroll
  for (int mt = 0; mt < 4; ++mt)
#pragma unroll
    for (int r = 0; r < 4; ++r) {
      int node = node0 + mt * 16 + q * 4 + r;
      xw[(size_t)node * HH_ + wave * 16 + n15] = acc2[mt][r];
    }
}

// ---- scatter: agg[b][dst] += xw[b][src] * dinv[s]*dinv[d]  (edges + self-loops)
__global__ void scatter_kernel(const int* __restrict__ ei, const float* __restrict__ dinv,
                               const float* __restrict__ xw, float* __restrict__ agg) {
  int gid = blockIdx.x * 256 + threadIdx.x;
  int j = gid & 127;
  int e = gid >> 7;
  if (e >= EE_ + NN_) return;
  int s, d;
  if (e < EE_) { s = ei[e]; d = ei[EE_ + e]; } else { s = e - EE_; d = s; }
  float w = dinv[s] * dinv[d];
#pragma unroll
  for (int b = 0; b < NB_; ++b) {
    float v = xw[((size_t)b * NN_ + s) * 128 + j] * w;
    atomicAdd(&agg[((size_t)b * NN_ + d) * 128 + j], v);
  }
}

// ---- MLP head: out = silu(agg@W1+b1)@W2 + b2
__global__ void mlp_kernel(const float* __restrict__ agg, const float* __restrict__ W1,
                           const float* __restrict__ b1, const float* __restrict__ W2,
                           const float* __restrict__ b2, float* __restrict__ out) {
  __shared__ float W1s[128 * 64];
  __shared__ float b1s[64];
  __shared__ float W2s[64];
  int tid = threadIdx.x;
  for (int i = tid; i < 128 * 64; i += 256) W1s[i] = W1[i];
  if (tid < 64) { b1s[tid] = b1[tid]; W2s[tid] = W2[tid]; }
  __syncthreads();
  int node = blockIdx.x * 256 + tid;
  if (node >= 16000) return;
  float acc[64];
#pragma unroll
  for (int j = 0; j < 64; ++j) acc[j] = b1s[j];
  const float4* arow = (const float4*)(agg + (size_t)node * 128);
  for (int kc = 0; kc < 32; ++kc) {
    float4 a = arow[kc];
#pragma unroll
    for (int kk = 0; kk < 4; ++kk) {
      float av = (kk == 0) ? a.x : (kk == 1) ? a.y : (kk == 2) ? a.z : a.w;
      int k = kc * 4 + kk;
#pragma unroll
      for (int j = 0; j < 64; j += 4) {
        float4 w = *(const float4*)&W1s[k * 64 + j];
        acc[j]     += av * w.x;
        acc[j + 1] += av * w.y;
        acc[j + 2] += av * w.z;
        acc[j + 3] += av * w.w;
      }
    }
  }
  float o = b2[0];
#pragma unroll
  for (int j = 0; j < 64; ++j) {
    float h = acc[j];
    float s = h * __builtin_amdgcn_rcpf(1.f + __builtin_amdgcn_exp2f(-1.44269504f * h));
    o += s * W2s[j];
  }
  out[node] = o;
}

extern "C" void kernel_launch(void* const* d_in, const int* in_sizes, int n_in,
                              void* d_out, int out_size, void* d_ws, size_t ws_size,
                              hipStream_t stream) {
  const float* x    = (const float*)d_in[0];
  const int*   ei   = (const int*)d_in[1];
  const float* Wih  = (const float*)d_in[2];
  const float* Whh  = (const float*)d_in[3];
  const float* bih  = (const float*)d_in[4];
  const float* bhh  = (const float*)d_in[5];
  const float* gcnW = (const float*)d_in[6];
  const float* gcnb = (const float*)d_in[7];
  const float* W1   = (const float*)d_in[8];
  const float* b1   = (const float*)d_in[9];
  const float* W2   = (const float*)d_in[10];
  const float* b2   = (const float*)d_in[11];
  float* out = (float*)d_out;
  char* ws = (char*)d_ws;

  _Float16* W16  = (_Float16*)(ws);                         // 512*160*2 = 163840
  _Float16* Wg16 = (_Float16*)(ws + 163840);                // 128*128*2 = 32768
  float*    bias = (float*)(ws + 196608);                   // 512*4     = 2048
  float*    xw   = (float*)(ws + 198656);                   // 16000*128*4 = 8192000
  float*    agg  = (float*)(ws + 198656 + 8192000);         // 8192000
  float*    deg  = (float*)(ws + 198656 + 2 * 8192000);     // 8192 (padded)
  float*    dinv = (float*)(ws + 198656 + 2 * 8192000 + 8192);

  prep_kernel<<<386, 256, 0, stream>>>(Wih, Whh, bih, bhh, gcnW, W16, Wg16, bias);
  init_kernel<<<8000, 256, 0, stream>>>(agg, deg, gcnb);
  deg_kernel<<<133, 256, 0, stream>>>(ei, deg);
  dinv_kernel<<<8, 256, 0, stream>>>(deg, dinv);
  lstm_gcn_kernel<<<250, 512, 0, stream>>>(x, W16, bias, Wg16, xw);
  scatter_kernel<<<17000, 256, 0, stream>>>(ei, dinv, xw, agg);
  mlp_kernel<<<63, 256, 0, stream>>>(agg, W1, b1, W2, b2, out);
}

// Round 2
// 463.730 us; speedup vs baseline: 1.2312x; 1.2312x over previous
//
#include <hip/hip_runtime.h>

typedef _Float16 f16x8 __attribute__((ext_vector_type(8)));
typedef _Float16 f16x4 __attribute__((ext_vector_type(4)));
typedef _Float16 f16x2 __attribute__((ext_vector_type(2)));
typedef float f32x4 __attribute__((ext_vector_type(4)));

#define NB_   8
#define NN_   2000
#define TT_   64
#define FF_   32
#define HH_   128
#define EE_   32000
#define KD    160     // F + H
#define KP    168     // padded LDS row in fp16 elems (336 B)
#define NODES 64
#define GSTR  (32 * KP)   // group stride in LDS elems

__device__ __forceinline__ float fexp2(float v) { return __builtin_amdgcn_exp2f(v); }
__device__ __forceinline__ float frcp(float v)  { return __builtin_amdgcn_rcpf(v); }

// ---- prep: pack pre-scaled [Wih|Whh] -> fp16 [512][160], gcn_W^T -> fp16, bias, deg=0
// rows [0,128)+[128,256)+[384,512) (i,f,o): * -1.44269504 ; rows [256,384) (g): * -2.88539008
__global__ void prep_kernel(const float* __restrict__ Wih, const float* __restrict__ Whh,
                            const float* __restrict__ bih, const float* __restrict__ bhh,
                            const float* __restrict__ gcnW,
                            _Float16* __restrict__ W16, _Float16* __restrict__ Wg16,
                            float* __restrict__ bias, float* __restrict__ deg) {
  int idx = blockIdx.x * 256 + threadIdx.x;
  if (idx < 512 * KD) {
    int col = idx / KD, k = idx % KD;
    float v = (k < 32) ? Wih[col * 32 + k] : Whh[col * 128 + (k - 32)];
    float sc = (col >= 256 && col < 384) ? -2.88539008f : -1.44269504f;
    W16[idx] = (_Float16)(v * sc);
  } else if (idx < 512 * KD + 128 * 128) {
    int i2 = idx - 512 * KD;
    int colg = i2 >> 7, k = i2 & 127;
    Wg16[i2] = (_Float16)gcnW[k * 128 + colg];   // Wg16[c][k] = gcnW[k][c]
  } else if (idx < 512 * KD + 128 * 128 + 512) {
    int i3 = idx - (512 * KD + 128 * 128);
    float sc = (i3 >= 256 && i3 < 384) ? -2.88539008f : -1.44269504f;
    bias[i3] = (bih[i3] + bhh[i3]) * sc;
  } else if (idx < 512 * KD + 128 * 128 + 512 + NN_) {
    deg[idx - (512 * KD + 128 * 128 + 512)] = 0.f;
  }
}

__global__ void deg_kernel(const int* __restrict__ ei, float* __restrict__ deg) {
  int e = blockIdx.x * 256 + threadIdx.x;
  if (e < EE_ + NN_) {
    int d = (e < EE_) ? ei[EE_ + e] : (e - EE_);
    atomicAdd(&deg[d], 1.f);
  }
}

__global__ void dinv_kernel(const float* __restrict__ deg, float* __restrict__ dinv) {
  int n = blockIdx.x * 256 + threadIdx.x;
  if (n < NN_) {
    float d = deg[n];
    dinv[n] = (d > 0.f) ? __builtin_amdgcn_rsqf(d) : 0.f;
  }
}

// ---- exclusive scan of edge-counts (deg-1) over 2000 dsts; one block
__global__ void scan_kernel(const float* __restrict__ deg, int* __restrict__ offs,
                            int* __restrict__ cursor) {
  __shared__ int s0[2048], s1[2048];
  int t = threadIdx.x;
  for (int i = t; i < 2048; i += 1024) s0[i] = (i < NN_) ? ((int)deg[i] - 1) : 0;
  __syncthreads();
  int* src = s0; int* dst = s1;
  for (int off = 1; off < 2048; off <<= 1) {
    for (int i = t; i < 2048; i += 1024)
      dst[i] = src[i] + ((i >= off) ? src[i - off] : 0);
    __syncthreads();
    int* tmp = src; src = dst; dst = tmp;
  }
  for (int i = t; i < NN_; i += 1024) {
    int exc = src[i] - ((int)deg[i] - 1);
    offs[i] = exc;
    cursor[i] = exc;
  }
}

__global__ void fill_kernel(const int* __restrict__ ei, const float* __restrict__ dinv,
                            int* __restrict__ cursor, int* __restrict__ csr_src,
                            float* __restrict__ csr_w) {
  int e = blockIdx.x * 256 + threadIdx.x;
  if (e >= EE_) return;
  int s = ei[e], d = ei[EE_ + e];
  int pos = atomicAdd(&cursor[d], 1);
  csr_src[pos] = s;
  csr_w[pos] = dinv[s] * dinv[d];
}

// ---- fused LSTM + GCN-GEMM, X/Y pipelined: MFMA(one group) overlaps gates(other)
__global__ __launch_bounds__(512, 2) void lstm_gcn_kernel(
    const float* __restrict__ x, const _Float16* __restrict__ W16,
    const float* __restrict__ bias, const _Float16* __restrict__ Wg16,
    float* __restrict__ xw) {
  __shared__ _Float16 A[NODES * KP];   // 21504 B
  const int tid  = threadIdx.x;
  const int wave = tid >> 6;
  const int lane = tid & 63;
  const int n15  = lane & 15;
  const int q    = lane >> 4;
  const int node0 = blockIdx.x * NODES;

  // weight A-fragments (rows = gate dims 128g + 16*wave + n15), pre-scaled
  f16x8 Af[4][5];
  float4 bgv[4];
#pragma unroll
  for (int g = 0; g < 4; ++g) {
    const int row = g * 128 + wave * 16 + n15;
#pragma unroll
    for (int kc = 0; kc < 5; ++kc)
      Af[g][kc] = *(const f16x8*)(W16 + row * KD + kc * 32 + q * 8);
    bgv[g] = *(const float4*)(bias + g * 128 + wave * 16 + q * 4);
  }

  // x staging: thread stages 2 floats of one node-row per phase
  const int xrow = tid >> 4;          // 0..31 within group
  const int xf   = (tid & 15) * 2;
  const float* xbase[2] = {
    x + (size_t)(node0 + xrow) * (TT_ * FF_) + xf,
    x + (size_t)(node0 + 32 + xrow) * (TT_ * FF_) + xf };
  _Float16* xlds[2] = { A + xrow * KP + xf, A + GSTR + xrow * KP + xf };

  const int hoff = n15 * KP + 32 + wave * 16 + q * 4;   // h-write base (elems)

  // h = 0, stage x(t=0) for both groups
  for (int i = tid; i < NODES * HH_; i += 512)
    A[(i >> 7) * KP + 32 + (i & 127)] = (_Float16)0.f;
  {
    float2 v0 = *(const float2*)(xbase[0]);
    float2 v1 = *(const float2*)(xbase[1]);
    f16x2 p0 = { (_Float16)v0.x, (_Float16)v0.y };
    f16x2 p1 = { (_Float16)v1.x, (_Float16)v1.y };
    *(f16x2*)xlds[0] = p0;
    *(f16x2*)xlds[1] = p1;
  }
  __syncthreads();

  f32x4 accX[2][4], accY[2][4], cX[2], cY[2];
#pragma unroll
  for (int nt = 0; nt < 2; ++nt) { cX[nt] = (f32x4){0,0,0,0}; cY[nt] = (f32x4){0,0,0,0}; }

  // z = W16 (A-op) x inputs (B-op) + bias ; D[row=gd_in_tile][col=node]
  auto mfma_group = [&](const _Float16* Ab, f32x4 (&acc)[2][4]) {
#pragma unroll
    for (int nt = 0; nt < 2; ++nt)
#pragma unroll
      for (int g = 0; g < 4; ++g)
        acc[nt][g] = (f32x4){bgv[g].x, bgv[g].y, bgv[g].z, bgv[g].w};
#pragma unroll
    for (int kc = 0; kc < 5; ++kc) {
      f16x8 bf[2];
#pragma unroll
      for (int nt = 0; nt < 2; ++nt)
        bf[nt] = *(const f16x8*)(Ab + (nt * 16 + n15) * KP + kc * 32 + q * 8);
#pragma unroll
      for (int nt = 0; nt < 2; ++nt)
#pragma unroll
        for (int g = 0; g < 4; ++g)
          acc[nt][g] = __builtin_amdgcn_mfma_f32_16x16x32_f16(Af[g][kc], bf[nt], acc[nt][g], 0, 0, 0);
    }
  };

  // gates on pre-scaled z: sigma = rcp(1+exp2(z')), tanh = 2*rcp(1+exp2(z''))-1
  auto gates = [&](_Float16* hb, f32x4 (&acc)[2][4], f32x4 (&c)[2]) {
#pragma unroll
    for (int nt = 0; nt < 2; ++nt) {
      f16x4 hv;
#pragma unroll
      for (int r = 0; r < 4; ++r) {
        float si = frcp(1.f + fexp2(acc[nt][0][r]));
        float sf = frcp(1.f + fexp2(acc[nt][1][r]));
        float tg = 2.f * frcp(1.f + fexp2(acc[nt][2][r])) - 1.f;
        float so = frcp(1.f + fexp2(acc[nt][3][r]));
        float cn = sf * c[nt][r] + si * tg;
        c[nt][r] = cn;
        float tc = 2.f * frcp(1.f + fexp2(-2.88539008f * cn)) - 1.f;
        hv[r] = (_Float16)(so * tc);
      }
      *(f16x4*)(hb + nt * (16 * KP)) = hv;
    }
  };

  mfma_group(A, accX);               // z_X(0)
  __syncthreads();

  for (int t = 0; t < TT_; ++t) {
    const bool more = (t + 1 < TT_);
    // phase A: gates X(t) + stage x_X(t+1) + MFMA Y(t)
    {
      float2 xv;
      if (more) xv = *(const float2*)(xbase[0] + (t + 1) * FF_);
      gates(A + hoff, accX, cX);
      if (more) { f16x2 p = { (_Float16)xv.x, (_Float16)xv.y }; *(f16x2*)xlds[0] = p; }
      mfma_group(A + GSTR, accY);    // z_Y(t)
    }
    __syncthreads();
    // phase B: gates Y(t) + stage x_Y(t+1) + MFMA X(t+1)
    {
      float2 xv;
      if (more) xv = *(const float2*)(xbase[1] + (t + 1) * FF_);
      gates(A + GSTR + hoff, accY, cY);
      if (more) { f16x2 p = { (_Float16)xv.x, (_Float16)xv.y }; *(f16x2*)xlds[1] = p; }
      if (more) mfma_group(A, accX); // z_X(t+1)
    }
    __syncthreads();
  }

  // epilogue: xw[node][c] = sum_k h[node][k] * gcnW[k][c]; Wg as A-op, h as B-op
  f16x8 Ag[4];
#pragma unroll
  for (int kc = 0; kc < 4; ++kc)
    Ag[kc] = *(const f16x8*)(Wg16 + (wave * 16 + n15) * HH_ + kc * 32 + q * 8);
  f32x4 acc2[4];
#pragma unroll
  for (int nt = 0; nt < 4; ++nt) acc2[nt] = (f32x4){0, 0, 0, 0};
#pragma unroll
  for (int kc = 0; kc < 4; ++kc)
#pragma unroll
    for (int nt = 0; nt < 4; ++nt) {
      f16x8 bf = *(const f16x8*)(&A[(nt * 16 + n15) * KP + 32 + kc * 32 + q * 8]);
      acc2[nt] = __builtin_amdgcn_mfma_f32_16x16x32_f16(Ag[kc], bf, acc2[nt], 0, 0, 0);
    }
#pragma unroll
  for (int nt = 0; nt < 4; ++nt)
    *(float4*)(xw + (size_t)(node0 + nt * 16 + n15) * HH_ + wave * 16 + q * 4) =
        (float4){acc2[nt][0], acc2[nt][1], acc2[nt][2], acc2[nt][3]};
}

// ---- CSR gather (no atomics): agg[b][d][:] = sum_e w_e*xw[b][s_e][:] + dinv[d]^2*xw[b][d][:] + gcn_b
__global__ void gather_kernel(const float* __restrict__ xw, const int* __restrict__ offs,
                              const float* __restrict__ deg, const float* __restrict__ dinv,
                              const int* __restrict__ csr_src, const float* __restrict__ csr_w,
                              const float* __restrict__ gcnb, float* __restrict__ agg) {
  const int d  = blockIdx.x;
  const int j  = threadIdx.x & 127;
  const int bh = threadIdx.x >> 7;       // batches bh*4 .. bh*4+3
  const int beg = offs[d];
  const int cnt = (int)deg[d] - 1;
  const size_t bbase = (size_t)(bh * 4) * NN_ * 128;
  float a0 = 0.f, a1 = 0.f, a2 = 0.f, a3 = 0.f;
  for (int e = 0; e < cnt; ++e) {
    int s   = csr_src[beg + e];
    float w = csr_w[beg + e];
    const float* p = xw + bbase + (size_t)s * 128 + j;
    a0 += w * p[0];
    a1 += w * p[NN_ * 128];
    a2 += w * p[2 * NN_ * 128];
    a3 += w * p[3 * NN_ * 128];
  }
  {
    float di = dinv[d];
    float w = di * di;
    const float* p = xw + bbase + (size_t)d * 128 + j;
    a0 += w * p[0];
    a1 += w * p[NN_ * 128];
    a2 += w * p[2 * NN_ * 128];
    a3 += w * p[3 * NN_ * 128];
  }
  float bj = gcnb[j];
  float* o = agg + bbase + (size_t)d * 128 + j;
  o[0] = a0 + bj;
  o[NN_ * 128] = a1 + bj;
  o[2 * NN_ * 128] = a2 + bj;
  o[3 * NN_ * 128] = a3 + bj;
}

// ---- MLP head: out = silu(agg@W1+b1)@W2 + b2
__global__ void mlp_kernel(const float* __restrict__ agg, const float* __restrict__ W1,
                           const float* __restrict__ b1, const float* __restrict__ W2,
                           const float* __restrict__ b2, float* __restrict__ out) {
  __shared__ float W1s[128 * 64];
  __shared__ float b1s[64];
  __shared__ float W2s[64];
  int tid = threadIdx.x;
  for (int i = tid; i < 128 * 64; i += 256) W1s[i] = W1[i];
  if (tid < 64) { b1s[tid] = b1[tid]; W2s[tid] = W2[tid]; }
  __syncthreads();
  int node = blockIdx.x * 256 + tid;
  if (node >= NB_ * NN_) return;
  float acc[64];
#pragma unroll
  for (int j = 0; j < 64; ++j) acc[j] = b1s[j];
  const float4* arow = (const float4*)(agg + (size_t)node * 128);
  for (int kc = 0; kc < 32; ++kc) {
    float4 a = arow[kc];
#pragma unroll
    for (int kk = 0; kk < 4; ++kk) {
      float av = (kk == 0) ? a.x : (kk == 1) ? a.y : (kk == 2) ? a.z : a.w;
      int k = kc * 4 + kk;
#pragma unroll
      for (int j = 0; j < 64; j += 4) {
        float4 w = *(const float4*)&W1s[k * 64 + j];
        acc[j]     += av * w.x;
        acc[j + 1] += av * w.y;
        acc[j + 2] += av * w.z;
        acc[j + 3] += av * w.w;
      }
    }
  }
  float o = b2[0];
#pragma unroll
  for (int j = 0; j < 64; ++j) {
    float h = acc[j];
    float s = h * frcp(1.f + fexp2(-1.44269504f * h));
    o += s * W2s[j];
  }
  out[node] = o;
}

extern "C" void kernel_launch(void* const* d_in, const int* in_sizes, int n_in,
                              void* d_out, int out_size, void* d_ws, size_t ws_size,
                              hipStream_t stream) {
  const float* x    = (const float*)d_in[0];
  const int*   ei   = (const int*)d_in[1];
  const float* Wih  = (const float*)d_in[2];
  const float* Whh  = (const float*)d_in[3];
  const float* bih  = (const float*)d_in[4];
  const float* bhh  = (const float*)d_in[5];
  const float* gcnW = (const float*)d_in[6];
  const float* gcnb = (const float*)d_in[7];
  const float* W1   = (const float*)d_in[8];
  const float* b1   = (const float*)d_in[9];
  const float* W2   = (const float*)d_in[10];
  const float* b2   = (const float*)d_in[11];
  float* out = (float*)d_out;
  char* ws = (char*)d_ws;

  _Float16* W16    = (_Float16*)(ws);                    // 163840
  _Float16* Wg16   = (_Float16*)(ws + 163840);           // 32768
  float*    bias   = (float*)(ws + 196608);              // 2048
  float*    xw     = (float*)(ws + 198656);              // 8192000
  float*    agg    = (float*)(ws + 8390656);             // 8192000
  float*    deg    = (float*)(ws + 16582656);            // 8192
  float*    dinv   = (float*)(ws + 16590848);            // 8192
  int*      offs   = (int*)(ws + 16599040);              // 8192
  int*      cursor = (int*)(ws + 16607232);              // 8192
  int*      csrs   = (int*)(ws + 16615424);              // 128000
  float*    csrw   = (float*)(ws + 16743424);            // 128000

  prep_kernel<<<394, 256, 0, stream>>>(Wih, Whh, bih, bhh, gcnW, W16, Wg16, bias, deg);
  deg_kernel<<<133, 256, 0, stream>>>(ei, deg);
  dinv_kernel<<<8, 256, 0, stream>>>(deg, dinv);
  scan_kernel<<<1, 1024, 0, stream>>>(deg, offs, cursor);
  fill_kernel<<<125, 256, 0, stream>>>(ei, dinv, cursor, csrs, csrw);
  lstm_gcn_kernel<<<250, 512, 0, stream>>>(x, W16, bias, Wg16, xw);
  gather_kernel<<<NN_, 256, 0, stream>>>(xw, offs, deg, dinv, csrs, csrw, gcnb, agg);
  mlp_kernel<<<63, 256, 0, stream>>>(agg, W1, b1, W2, b2, out);
}

// Round 3
// 423.632 us; speedup vs baseline: 1.3477x; 1.0947x over previous
//
#include <hip/hip_runtime.h>

typedef _Float16 f16x8 __attribute__((ext_vector_type(8)));
typedef _Float16 f16x4 __attribute__((ext_vector_type(4)));
typedef _Float16 f16x2 __attribute__((ext_vector_type(2)));
typedef float f32x4 __attribute__((ext_vector_type(4)));

#define NB_   8
#define NN_   2000
#define TT_   64
#define FF_   32
#define HH_   128
#define EE_   32000
#define KD    160        // F + H
#define RSTR  192        // swizzled LDS row stride (f16 elems), 24 chunks of 8
#define GELEM (32*RSTR)  // group offset in elems (group Y)

__device__ __forceinline__ float fexp2(float v) { return __builtin_amdgcn_exp2f(v); }
__device__ __forceinline__ float frcp(float v)  { return __builtin_amdgcn_rcpf(v); }

// ---- prep: pack pre-scaled [Wih|Whh] -> fp16 [512][160], gcn_W^T -> fp16, bias, deg=0
// gate rows i,f,o: * -1.44269504 ; g rows [256,384): * -2.88539008
__global__ void prep_kernel(const float* __restrict__ Wih, const float* __restrict__ Whh,
                            const float* __restrict__ bih, const float* __restrict__ bhh,
                            const float* __restrict__ gcnW,
                            _Float16* __restrict__ W16, _Float16* __restrict__ Wg16,
                            float* __restrict__ bias, float* __restrict__ deg) {
  int idx = blockIdx.x * 256 + threadIdx.x;
  if (idx < 512 * KD) {
    int col = idx / KD, k = idx % KD;
    float v = (k < 32) ? Wih[col * 32 + k] : Whh[col * 128 + (k - 32)];
    float sc = (col >= 256 && col < 384) ? -2.88539008f : -1.44269504f;
    W16[idx] = (_Float16)(v * sc);
  } else if (idx < 512 * KD + 128 * 128) {
    int i2 = idx - 512 * KD;
    int colg = i2 >> 7, k = i2 & 127;
    Wg16[i2] = (_Float16)gcnW[k * 128 + colg];   // Wg16[c][k] = gcnW[k][c]
  } else if (idx < 512 * KD + 128 * 128 + 512) {
    int i3 = idx - (512 * KD + 128 * 128);
    float sc = (i3 >= 256 && i3 < 384) ? -2.88539008f : -1.44269504f;
    bias[i3] = (bih[i3] + bhh[i3]) * sc;
  } else if (idx < 512 * KD + 128 * 128 + 512 + NN_) {
    deg[idx - (512 * KD + 128 * 128 + 512)] = 0.f;
  }
}

__global__ void deg_kernel(const int* __restrict__ ei, float* __restrict__ deg) {
  int e = blockIdx.x * 256 + threadIdx.x;
  if (e < EE_ + NN_) {
    int d = (e < EE_) ? ei[EE_ + e] : (e - EE_);
    atomicAdd(&deg[d], 1.f);
  }
}

__global__ void dinv_kernel(const float* __restrict__ deg, float* __restrict__ dinv) {
  int n = blockIdx.x * 256 + threadIdx.x;
  if (n < NN_) {
    float d = deg[n];
    dinv[n] = (d > 0.f) ? __builtin_amdgcn_rsqf(d) : 0.f;
  }
}

// ---- exclusive scan of edge-counts (deg-1) over 2000 dsts; one block
__global__ void scan_kernel(const float* __restrict__ deg, int* __restrict__ offs,
                            int* __restrict__ cursor) {
  __shared__ int s0[2048], s1[2048];
  int t = threadIdx.x;
  for (int i = t; i < 2048; i += 1024) s0[i] = (i < NN_) ? ((int)deg[i] - 1) : 0;
  __syncthreads();
  int* src = s0; int* dst = s1;
  for (int off = 1; off < 2048; off <<= 1) {
    for (int i = t; i < 2048; i += 1024)
      dst[i] = src[i] + ((i >= off) ? src[i - off] : 0);
    __syncthreads();
    int* tmp = src; src = dst; dst = tmp;
  }
  for (int i = t; i < NN_; i += 1024) {
    int exc = src[i] - ((int)deg[i] - 1);
    offs[i] = exc;
    cursor[i] = exc;
  }
}

__global__ void fill_kernel(const int* __restrict__ ei, const float* __restrict__ dinv,
                            int* __restrict__ cursor, int* __restrict__ csr_src,
                            float* __restrict__ csr_w) {
  int e = blockIdx.x * 256 + threadIdx.x;
  if (e >= EE_) return;
  int s = ei[e], d = ei[EE_ + e];
  int pos = atomicAdd(&cursor[d], 1);
  csr_src[pos] = s;
  csr_w[pos] = dinv[s] * dinv[d];
}

// ---- fused LSTM + GCN-GEMM. 250 blocks x 512 thr, 64 nodes (X/Y groups of 32).
// LDS layout: elem(row,k) = row*192 + (((k>>3) ^ (row&7))<<3) + (k&7)  (XOR swizzle,
// conflict-free for b128 B-frag reads / b64 h-writes / b32 x-stage).
// Phase interleave: mfma_half issues 20 MFMAs (no deps on this phase's gates), then
// gates_half's ~600-cyc VALU chain runs while the matrix pipe drains.
__global__ __launch_bounds__(512, 2) void lstm_gcn_kernel(
    const float* __restrict__ x, const _Float16* __restrict__ W16,
    const float* __restrict__ bias, const _Float16* __restrict__ Wg16,
    float* __restrict__ xw) {
  __shared__ _Float16 A[64 * RSTR];   // 24576 B
  const int tid  = threadIdx.x;
  const int wave = tid >> 6;
  const int lane = tid & 63;
  const int n15  = lane & 15;
  const int q    = lane >> 4;
  const int m    = n15 & 7;
  const int hm   = m >> 2;
  const int qx   = q ^ (m & 3);
  const int node0 = blockIdx.x * 64;

  // weight A-fragments (rows = gate dims g*128 + wave*16 + n15), pre-scaled
  f16x8 Af[4][5];
  float4 bgv[4];
#pragma unroll
  for (int g = 0; g < 4; ++g) {
    const int row = g * 128 + wave * 16 + n15;
#pragma unroll
    for (int kc = 0; kc < 5; ++kc)
      Af[g][kc] = *(const f16x8*)(W16 + row * KD + kc * 32 + q * 8);
    bgv[g] = *(const float4*)(bias + g * 128 + wave * 16 + q * 4);
  }

  // per-lane LDS offsets
  const int bRow = n15 * RSTR + (qx << 3);  // B-frag: + (kc^hm)<<5 + nt*16*RSTR + G
  const int hOff = n15 * RSTR + (((4 + 2 * wave + (q >> 1)) ^ m) << 3) + ((q & 1) << 2);

  // x staging: thread stages 2 floats of one node-row per group per phase
  const int xrow = tid >> 4;          // 0..31
  const int xf   = (tid & 15) * 2;
  const int xOff = xrow * RSTR + (((xf >> 3) ^ (xrow & 7)) << 3) + (xf & 7);
  const float* xb0 = x + (size_t)(node0 + xrow) * (TT_ * FF_) + xf;
  const float* xb1 = x + (size_t)(node0 + 32 + xrow) * (TT_ * FF_) + xf;

  // h = 0 (both groups)
  for (int i = tid; i < 1024; i += 512) {
    int row = i >> 4, ci = i & 15;
    f16x8 z8 = {(_Float16)0, (_Float16)0, (_Float16)0, (_Float16)0,
                (_Float16)0, (_Float16)0, (_Float16)0, (_Float16)0};
    *(f16x8*)(A + row * RSTR + (((4 + ci) ^ (row & 7)) << 3)) = z8;
  }
  // stage x(t=0)
  {
    float2 v0 = *(const float2*)xb0;
    float2 v1 = *(const float2*)xb1;
    f16x2 p0 = {(_Float16)v0.x, (_Float16)v0.y};
    f16x2 p1 = {(_Float16)v1.x, (_Float16)v1.y};
    *(f16x2*)(A + xOff) = p0;
    *(f16x2*)(A + GELEM + xOff) = p1;
  }
  __syncthreads();

  f32x4 accX[2][4], accY[2][4], cX[2], cY[2];
#pragma unroll
  for (int nt = 0; nt < 2; ++nt) { cX[nt] = (f32x4){0,0,0,0}; cY[nt] = (f32x4){0,0,0,0}; }

  auto mfma_half = [&](int G, int nt, f32x4 (&acc)[4]) {
#pragma unroll
    for (int g = 0; g < 4; ++g)
      acc[g] = (f32x4){bgv[g].x, bgv[g].y, bgv[g].z, bgv[g].w};
#pragma unroll
    for (int kc = 0; kc < 5; ++kc) {
      f16x8 bf = *(const f16x8*)(A + G + nt * (16 * RSTR) + bRow + ((kc ^ hm) << 5));
#pragma unroll
      for (int g = 0; g < 4; ++g)
        acc[g] = __builtin_amdgcn_mfma_f32_16x16x32_f16(Af[g][kc], bf, acc[g], 0, 0, 0);
    }
  };

  // batched-rcp gates: one rcp per 4 gate-denoms, one per 4 tanh(c)-denoms
  auto gates_half = [&](int G, int nt, f32x4 (&acc)[4], f32x4& c) {
    const float EM = 2.68435456e8f;   // 2^28 clamp: keeps 4-denom product < 2^127
    float so[4], eC[4], dC[4];
#pragma unroll
    for (int r = 0; r < 4; ++r) {
      float ei = fminf(fexp2(acc[0][r]), EM);
      float ef = fminf(fexp2(acc[1][r]), EM);
      float eg = fminf(fexp2(acc[2][r]), EM);
      float eo = fminf(fexp2(acc[3][r]), EM);
      float di = 1.f + ei, df = 1.f + ef, dg = 1.f + eg, dd = 1.f + eo;
      float p0 = di * df, p1 = dg * dd;
      float rP = frcp(p0 * p1);
      float r0 = rP * p1, r1 = rP * p0;
      float si = r0 * df, sf = r0 * di;
      float tg = 2.f * (r1 * dd) - 1.f;
      so[r] = r1 * dg;
      c[r] = sf * c[r] + si * tg;
    }
#pragma unroll
    for (int r = 0; r < 4; ++r) {
      eC[r] = fminf(fexp2(-2.88539008f * c[r]), EM);
      dC[r] = 1.f + eC[r];
    }
    float q0 = dC[0] * dC[1], q1 = dC[2] * dC[3];
    float rQ = frcp(q0 * q1);
    float s0 = rQ * q1, s1 = rQ * q0;
    f16x4 hp = {(_Float16)(so[0] * (2.f * (s0 * dC[1]) - 1.f)),
                (_Float16)(so[1] * (2.f * (s0 * dC[0]) - 1.f)),
                (_Float16)(so[2] * (2.f * (s1 * dC[3]) - 1.f)),
                (_Float16)(so[3] * (2.f * (s1 * dC[2]) - 1.f))};
    *(f16x4*)(A + G + nt * (16 * RSTR) + hOff) = hp;
  };

  // prologue: z_X(0)
  mfma_half(0, 0, accX[0]);
  mfma_half(0, 1, accX[1]);
  __syncthreads();

  for (int t = 0; t < TT_; ++t) {
    const bool more = (t + 1 < TT_);
    // phase A: mfma Y(t) interleaved with gates X(t); stage x_X(t+1)
    {
      float2 xv;
      if (more) xv = *(const float2*)(xb0 + (t + 1) * FF_);
      mfma_half(GELEM, 0, accY[0]);
      gates_half(0, 0, accX[0], cX[0]);
      mfma_half(GELEM, 1, accY[1]);
      gates_half(0, 1, accX[1], cX[1]);
      if (more) { f16x2 p = {(_Float16)xv.x, (_Float16)xv.y}; *(f16x2*)(A + xOff) = p; }
    }
    __syncthreads();
    // phase B: mfma X(t+1) interleaved with gates Y(t); stage x_Y(t+1)
    {
      float2 xv;
      if (more) xv = *(const float2*)(xb1 + (t + 1) * FF_);
      if (more) mfma_half(0, 0, accX[0]);
      gates_half(GELEM, 0, accY[0], cY[0]);
      if (more) mfma_half(0, 1, accX[1]);
      gates_half(GELEM, 1, accY[1], cY[1]);
      if (more) { f16x2 p = {(_Float16)xv.x, (_Float16)xv.y}; *(f16x2*)(A + GELEM + xOff) = p; }
    }
    __syncthreads();
  }

  // epilogue: xw[node][c] = sum_k h[node][k] * gcnW[k][c]; Wg as A-op, h as B-op
  f16x8 Ag[4];
#pragma unroll
  for (int kc = 0; kc < 4; ++kc)
    Ag[kc] = *(const f16x8*)(Wg16 + (wave * 16 + n15) * HH_ + kc * 32 + q * 8);
  f32x4 acc2[4];
#pragma unroll
  for (int nt = 0; nt < 4; ++nt) acc2[nt] = (f32x4){0, 0, 0, 0};
#pragma unroll
  for (int kc = 0; kc < 4; ++kc)
#pragma unroll
    for (int nt = 0; nt < 4; ++nt) {
      f16x8 bf = *(const f16x8*)(A + (nt * 16 + n15) * RSTR +
                                 (((kc + 1) ^ hm) << 5) + (qx << 3));
      acc2[nt] = __builtin_amdgcn_mfma_f32_16x16x32_f16(Ag[kc], bf, acc2[nt], 0, 0, 0);
    }
#pragma unroll
  for (int nt = 0; nt < 4; ++nt)
    *(float4*)(xw + (size_t)(node0 + nt * 16 + n15) * HH_ + wave * 16 + q * 4) =
        (float4){acc2[nt][0], acc2[nt][1], acc2[nt][2], acc2[nt][3]};
}

// ---- fused CSR gather + MLP head: block per dst node
__global__ void gathermlp_kernel(const float* __restrict__ xw, const int* __restrict__ offs,
                                 const float* __restrict__ deg, const float* __restrict__ dinv,
                                 const int* __restrict__ csr_src, const float* __restrict__ csr_w,
                                 const float* __restrict__ gcnb,
                                 const float* __restrict__ W1, const float* __restrict__ b1,
                                 const float* __restrict__ W2, const float* __restrict__ b2,
                                 float* __restrict__ out) {
  __shared__ float aggs[8][128];
  const int d = blockIdx.x;
  const int tid = threadIdx.x;
  {
    const int j  = tid & 127;
    const int bh = tid >> 7;             // batches bh*4 .. bh*4+3
    const int beg = offs[d];
    const int cnt = (int)deg[d] - 1;
    const size_t bbase = (size_t)(bh * 4) * NN_ * 128;
    float a0 = 0.f, a1 = 0.f, a2 = 0.f, a3 = 0.f;
    for (int e = 0; e < cnt; ++e) {
      int s   = csr_src[beg + e];
      float w = csr_w[beg + e];
      const float* p = xw + bbase + (size_t)s * 128 + j;
      a0 += w * p[0];
      a1 += w * p[NN_ * 128];
      a2 += w * p[2 * NN_ * 128];
      a3 += w * p[3 * NN_ * 128];
    }
    {
      float di = dinv[d];
      float w = di * di;
      const float* p = xw + bbase + (size_t)d * 128 + j;
      a0 += w * p[0];
      a1 += w * p[NN_ * 128];
      a2 += w * p[2 * NN_ * 128];
      a3 += w * p[3 * NN_ * 128];
    }
    float bj = gcnb[j];
    aggs[bh * 4 + 0][j] = a0 + bj;
    aggs[bh * 4 + 1][j] = a1 + bj;
    aggs[bh * 4 + 2][j] = a2 + bj;
    aggs[bh * 4 + 3][j] = a3 + bj;
  }
  __syncthreads();
  // MLP: thread (b = tid>>5, t = tid&31) owns j2 = {t, t+32}
  const int b = tid >> 5;
  const int t = tid & 31;
  float acc1 = b1[t], acc2 = b1[t + 32];
#pragma unroll 4
  for (int k = 0; k < 128; ++k) {
    float a = aggs[b][k];
    acc1 += a * W1[k * 64 + t];
    acc2 += a * W1[k * 64 + t + 32];
  }
  float s1 = acc1 * frcp(1.f + fexp2(-1.44269504f * acc1));
  float s2 = acc2 * frcp(1.f + fexp2(-1.44269504f * acc2));
  float part = s1 * W2[t] + s2 * W2[t + 32];
#pragma unroll
  for (int msk = 16; msk >= 1; msk >>= 1) part += __shfl_xor(part, msk);
  if (t == 0) out[(size_t)b * NN_ + d] = part + b2[0];
}

extern "C" void kernel_launch(void* const* d_in, const int* in_sizes, int n_in,
                              void* d_out, int out_size, void* d_ws, size_t ws_size,
                              hipStream_t stream) {
  const float* x    = (const float*)d_in[0];
  const int*   ei   = (const int*)d_in[1];
  const float* Wih  = (const float*)d_in[2];
  const float* Whh  = (const float*)d_in[3];
  const float* bih  = (const float*)d_in[4];
  const float* bhh  = (const float*)d_in[5];
  const float* gcnW = (const float*)d_in[6];
  const float* gcnb = (const float*)d_in[7];
  const float* W1   = (const float*)d_in[8];
  const float* b1   = (const float*)d_in[9];
  const float* W2   = (const float*)d_in[10];
  const float* b2   = (const float*)d_in[11];
  float* out = (float*)d_out;
  char* ws = (char*)d_ws;

  _Float16* W16    = (_Float16*)(ws);                    // 163840
  _Float16* Wg16   = (_Float16*)(ws + 163840);           // 32768
  float*    bias   = (float*)(ws + 196608);              // 2048
  float*    xw     = (float*)(ws + 198656);              // 8192000
  float*    deg    = (float*)(ws + 8390656);             // 8192
  float*    dinv   = (float*)(ws + 8398848);             // 8192
  int*      offs   = (int*)(ws + 8407040);               // 8192
  int*      cursor = (int*)(ws + 8415232);               // 8192
  int*      csrs   = (int*)(ws + 8423424);               // 128000
  float*    csrw   = (float*)(ws + 8551424);             // 128000

  prep_kernel<<<394, 256, 0, stream>>>(Wih, Whh, bih, bhh, gcnW, W16, Wg16, bias, deg);
  deg_kernel<<<133, 256, 0, stream>>>(ei, deg);
  dinv_kernel<<<8, 256, 0, stream>>>(deg, dinv);
  scan_kernel<<<1, 1024, 0, stream>>>(deg, offs, cursor);
  fill_kernel<<<125, 256, 0, stream>>>(ei, dinv, cursor, csrs, csrw);
  lstm_gcn_kernel<<<250, 512, 0, stream>>>(x, W16, bias, Wg16, xw);
  gathermlp_kernel<<<NN_, 256, 0, stream>>>(xw, offs, deg, dinv, csrs, csrw,
                                            gcnb, W1, b1, W2, b2, out);
}

// Round 4
// 407.907 us; speedup vs baseline: 1.3997x; 1.0386x over previous
//
#include <hip/hip_runtime.h>

typedef _Float16 f16x8 __attribute__((ext_vector_type(8)));
typedef _Float16 f16x4 __attribute__((ext_vector_type(4)));
typedef _Float16 f16x2 __attribute__((ext_vector_type(2)));
typedef float f32x4 __attribute__((ext_vector_type(4)));

#define NB_   8
#define NN_   2000
#define TT_   64
#define FF_   32
#define HH_   128
#define EE_   32000
#define KD    160        // F + H
#define RSTR  192        // swizzled LDS row stride (f16 elems)
#define NODES 32         // nodes per block
#define WXSTR 40         // Wx LDS row stride (f16), 80 B -> 2-way max on A-frag reads

__device__ __forceinline__ float fexp2(float v) { return __builtin_amdgcn_exp2f(v); }
__device__ __forceinline__ float frcp(float v)  { return __builtin_amdgcn_rcpf(v); }

// ---- prep: pack pre-scaled [Wih|Whh] -> fp16 [512][160], gcn_W^T -> fp16, bias, deg=0
// gate rows i,f,o: * -1.44269504 ; g rows [256,384): * -2.88539008
__global__ void prep_kernel(const float* __restrict__ Wih, const float* __restrict__ Whh,
                            const float* __restrict__ bih, const float* __restrict__ bhh,
                            const float* __restrict__ gcnW,
                            _Float16* __restrict__ W16, _Float16* __restrict__ Wg16,
                            float* __restrict__ bias, float* __restrict__ deg) {
  int idx = blockIdx.x * 256 + threadIdx.x;
  if (idx < 512 * KD) {
    int col = idx / KD, k = idx % KD;
    float v = (k < 32) ? Wih[col * 32 + k] : Whh[col * 128 + (k - 32)];
    float sc = (col >= 256 && col < 384) ? -2.88539008f : -1.44269504f;
    W16[idx] = (_Float16)(v * sc);
  } else if (idx < 512 * KD + 128 * 128) {
    int i2 = idx - 512 * KD;
    int colg = i2 >> 7, k = i2 & 127;
    Wg16[i2] = (_Float16)gcnW[k * 128 + colg];   // Wg16[c][k] = gcnW[k][c]
  } else if (idx < 512 * KD + 128 * 128 + 512) {
    int i3 = idx - (512 * KD + 128 * 128);
    float sc = (i3 >= 256 && i3 < 384) ? -2.88539008f : -1.44269504f;
    bias[i3] = (bih[i3] + bhh[i3]) * sc;
  } else if (idx < 512 * KD + 128 * 128 + 512 + NN_) {
    deg[idx - (512 * KD + 128 * 128 + 512)] = 0.f;
  }
}

__global__ void deg_kernel(const int* __restrict__ ei, float* __restrict__ deg) {
  int e = blockIdx.x * 256 + threadIdx.x;
  if (e < EE_ + NN_) {
    int d = (e < EE_) ? ei[EE_ + e] : (e - EE_);
    atomicAdd(&deg[d], 1.f);
  }
}

// ---- exclusive scan of (deg-1) + dinv, one block
__global__ void scan_kernel(const float* __restrict__ deg, int* __restrict__ offs,
                            int* __restrict__ cursor, float* __restrict__ dinv) {
  __shared__ int s0[2048], s1[2048];
  int t = threadIdx.x;
  for (int i = t; i < 2048; i += 1024) s0[i] = (i < NN_) ? ((int)deg[i] - 1) : 0;
  __syncthreads();
  int* src = s0; int* dst = s1;
  for (int off = 1; off < 2048; off <<= 1) {
    for (int i = t; i < 2048; i += 1024)
      dst[i] = src[i] + ((i >= off) ? src[i - off] : 0);
    __syncthreads();
    int* tmp = src; src = dst; dst = tmp;
  }
  for (int i = t; i < NN_; i += 1024) {
    int exc = src[i] - ((int)deg[i] - 1);
    offs[i] = exc;
    cursor[i] = exc;
    float d = deg[i];
    dinv[i] = (d > 0.f) ? __builtin_amdgcn_rsqf(d) : 0.f;
  }
}

__global__ void fill_kernel(const int* __restrict__ ei, const float* __restrict__ dinv,
                            int* __restrict__ cursor, int* __restrict__ csr_src,
                            float* __restrict__ csr_w) {
  int e = blockIdx.x * 256 + threadIdx.x;
  if (e >= EE_) return;
  int s = ei[e], d = ei[EE_ + e];
  int pos = atomicAdd(&cursor[d], 1);
  csr_src[pos] = s;
  csr_w[pos] = dinv[s] * dinv[d];
}

// ---- fused LSTM + GCN-GEMM. 500 blocks x 512 thr, 32 nodes; 2 blocks/CU co-resident
// (cross-block MFMA/VALU overlap). Activation LDS XOR-swizzled as round 3. kc=0
// (x-features) weight A-frags + bias live in LDS so VGPR total fits 128/wave.
__global__ __launch_bounds__(512, 4) void lstm_gcn_kernel(
    const float* __restrict__ x, const _Float16* __restrict__ W16,
    const float* __restrict__ bias, const _Float16* __restrict__ Wg16,
    float* __restrict__ xwT) {
  __shared__ _Float16 A[NODES * RSTR];      // 12288 B
  __shared__ _Float16 WxL[512 * WXSTR];     // 40960 B
  __shared__ float    BiasL[512];           // 2048 B
  const int tid  = threadIdx.x;
  const int wave = tid >> 6;
  const int lane = tid & 63;
  const int n15  = lane & 15;
  const int q    = lane >> 4;
  const int m    = n15 & 7;
  const int hm   = m >> 2;
  const int qx   = q ^ (m & 3);
  const int node0 = blockIdx.x * NODES;

  // resident weight A-frags for K 32..159 (h-part): rows = gate dims g*128+wave*16+n15
  f16x8 Af[4][4];
#pragma unroll
  for (int g = 0; g < 4; ++g) {
    const int row = g * 128 + wave * 16 + n15;
#pragma unroll
    for (int kc = 1; kc < 5; ++kc)
      Af[g][kc - 1] = *(const f16x8*)(W16 + row * KD + kc * 32 + q * 8);
  }
  // Wx (K 0..31) + bias -> LDS
  {
    const _Float16* wr = W16 + tid * KD;
#pragma unroll
    for (int cch = 0; cch < 4; ++cch)
      *(f16x8*)(WxL + tid * WXSTR + cch * 8) = *(const f16x8*)(wr + cch * 8);
    if (tid < 128) *(float4*)(BiasL + tid * 4) = *(const float4*)(bias + tid * 4);
  }

  // per-lane LDS offsets (activation tile, XOR swizzle)
  const int bRow = n15 * RSTR + (qx << 3);   // + ((kc^hm)<<5) + nt*16*RSTR
  const int hOff = n15 * RSTR + (((4 + 2 * wave + (q >> 1)) ^ m) << 3) + ((q & 1) << 2);
  const int aRow = (wave * 16 + n15) * WXSTR + q * 8;   // Wx A-frag base (g*128*WXSTR step)

  // x staging: thread stages 2 floats of one node-row per step
  const int xrow = tid >> 4;          // 0..31
  const int xf   = (tid & 15) * 2;
  const int xOff = xrow * RSTR + (((xf >> 3) ^ (xrow & 7)) << 3) + (xf & 7);
  const float* xb = x + (size_t)(node0 + xrow) * (TT_ * FF_) + xf;

  // h = 0
  {
    int row = tid >> 4, ci = tid & 15;
    f16x8 z8 = {(_Float16)0, (_Float16)0, (_Float16)0, (_Float16)0,
                (_Float16)0, (_Float16)0, (_Float16)0, (_Float16)0};
    *(f16x8*)(A + row * RSTR + (((4 + ci) ^ (row & 7)) << 3)) = z8;
  }
  // stage x(0)
  {
    float2 v = *(const float2*)xb;
    f16x2 p = {(_Float16)v.x, (_Float16)v.y};
    *(f16x2*)(A + xOff) = p;
  }
  __syncthreads();

  f32x4 acc[2][4], c[2];
  c[0] = (f32x4){0, 0, 0, 0};
  c[1] = (f32x4){0, 0, 0, 0};

  for (int t = 0; t < TT_; ++t) {
    // ---- MFMA phase: z = W·[x;h] + bias
    {
      f32x4 bt[4];
#pragma unroll
      for (int g = 0; g < 4; ++g)
        bt[g] = *(const f32x4*)(BiasL + g * 128 + wave * 16 + q * 4);
#pragma unroll
      for (int nt = 0; nt < 2; ++nt)
#pragma unroll
        for (int g = 0; g < 4; ++g) acc[nt][g] = bt[g];
      f16x8 ax[4];
#pragma unroll
      for (int g = 0; g < 4; ++g)
        ax[g] = *(const f16x8*)(WxL + g * 128 * WXSTR + aRow);
#pragma unroll
      for (int nt = 0; nt < 2; ++nt) {
        f16x8 bf = *(const f16x8*)(A + nt * (16 * RSTR) + bRow + (hm << 5));  // kc=0
#pragma unroll
        for (int g = 0; g < 4; ++g)
          acc[nt][g] = __builtin_amdgcn_mfma_f32_16x16x32_f16(ax[g], bf, acc[nt][g], 0, 0, 0);
      }
#pragma unroll
      for (int kc = 1; kc < 5; ++kc)
#pragma unroll
        for (int nt = 0; nt < 2; ++nt) {
          f16x8 bf = *(const f16x8*)(A + nt * (16 * RSTR) + bRow + ((kc ^ hm) << 5));
#pragma unroll
          for (int g = 0; g < 4; ++g)
            acc[nt][g] = __builtin_amdgcn_mfma_f32_16x16x32_f16(Af[g][kc - 1], bf, acc[nt][g], 0, 0, 0);
        }
    }
    const bool more = (t + 1 < TT_);
    float2 xv;
    if (more) xv = *(const float2*)(xb + (t + 1) * FF_);
    __syncthreads();   // all LDS reads done before h/x writes

    // ---- gates phase (unbatched; rcp(inf)=0 handles saturation, no clamps)
#pragma unroll
    for (int nt = 0; nt < 2; ++nt) {
      f16x4 hp;
#pragma unroll
      for (int r = 0; r < 4; ++r) {
        float si = frcp(1.f + fexp2(acc[nt][0][r]));
        float sf = frcp(1.f + fexp2(acc[nt][1][r]));
        float tg = 2.f * frcp(1.f + fexp2(acc[nt][2][r])) - 1.f;
        float so = frcp(1.f + fexp2(acc[nt][3][r]));
        float cn = sf * c[nt][r] + si * tg;
        c[nt][r] = cn;
        float tc = 2.f * frcp(1.f + fexp2(-2.88539008f * cn)) - 1.f;
        hp[r] = (_Float16)(so * tc);
      }
      *(f16x4*)(A + nt * (16 * RSTR) + hOff) = hp;
    }
    if (more) { f16x2 p = {(_Float16)xv.x, (_Float16)xv.y}; *(f16x2*)(A + xOff) = p; }
    __syncthreads();
  }

  // ---- epilogue: xwT[(n*8+b)*128 + col] = sum_k h[node][k] * gcnW[k][col]
  f16x8 Ag[4];
#pragma unroll
  for (int kc = 0; kc < 4; ++kc)
    Ag[kc] = *(const f16x8*)(Wg16 + (wave * 16 + n15) * HH_ + kc * 32 + q * 8);
  f32x4 acc2[2];
  acc2[0] = (f32x4){0, 0, 0, 0};
  acc2[1] = (f32x4){0, 0, 0, 0};
#pragma unroll
  for (int kc = 0; kc < 4; ++kc)
#pragma unroll
    for (int nt = 0; nt < 2; ++nt) {
      f16x8 bf = *(const f16x8*)(A + nt * (16 * RSTR) + bRow + (((kc + 1) ^ hm) << 5));
      acc2[nt] = __builtin_amdgcn_mfma_f32_16x16x32_f16(Ag[kc], bf, acc2[nt], 0, 0, 0);
    }
#pragma unroll
  for (int nt = 0; nt < 2; ++nt) {
    int mnode = node0 + nt * 16 + n15;
    int b = mnode / NN_;
    int n = mnode - b * NN_;
    *(float4*)(xwT + ((size_t)n * 8 + b) * HH_ + wave * 16 + q * 4) =
        (float4){acc2[nt][0], acc2[nt][1], acc2[nt][2], acc2[nt][3]};
  }
}

// ---- fused CSR gather + MLP head: block per dst node; xwT is [node][batch][dim]
__global__ __launch_bounds__(256) void gathermlp_kernel(
    const float* __restrict__ xwT, const int* __restrict__ offs,
    const float* __restrict__ deg, const float* __restrict__ dinv,
    const int* __restrict__ csr_src, const float* __restrict__ csr_w,
    const float* __restrict__ gcnb,
    const float* __restrict__ W1, const float* __restrict__ b1,
    const float* __restrict__ W2, const float* __restrict__ b2,
    float* __restrict__ out) {
  __shared__ float aggs[8][128];
  __shared__ float W1T[64][132];            // W1T[j][k] = W1[k*64+j]; pad 132 vs bank conflicts
  const int d = blockIdx.x;
  const int tid = threadIdx.x;
  for (int i = tid; i < 8192; i += 256) {
    int k = i >> 6, j = i & 63;
    W1T[j][k] = W1[i];
  }
  {
    const int j  = tid & 127;
    const int bh = tid >> 7;                // batch-half: batches bh*4 .. bh*4+3
    const int beg = offs[d];
    const int cnt = (int)deg[d] - 1;
    const int boff = bh * 512 + j;
    float a0 = 0.f, a1 = 0.f, a2 = 0.f, a3 = 0.f;
    int e = 0;
    for (; e + 1 < cnt; e += 2) {           // 2-edge unroll: 8 loads in flight
      int s0 = csr_src[beg + e],     s1 = csr_src[beg + e + 1];
      float w0 = csr_w[beg + e],     w1 = csr_w[beg + e + 1];
      const float* p0 = xwT + (size_t)s0 * 1024 + boff;
      const float* p1 = xwT + (size_t)s1 * 1024 + boff;
      float v00 = p0[0], v01 = p0[128], v02 = p0[256], v03 = p0[384];
      float v10 = p1[0], v11 = p1[128], v12 = p1[256], v13 = p1[384];
      a0 += w0 * v00 + w1 * v10;
      a1 += w0 * v01 + w1 * v11;
      a2 += w0 * v02 + w1 * v12;
      a3 += w0 * v03 + w1 * v13;
    }
    if (e < cnt) {
      int s = csr_src[beg + e];
      float w = csr_w[beg + e];
      const float* p = xwT + (size_t)s * 1024 + boff;
      a0 += w * p[0]; a1 += w * p[128]; a2 += w * p[256]; a3 += w * p[384];
    }
    {
      float di = dinv[d];
      float w = di * di;
      const float* p = xwT + (size_t)d * 1024 + boff;
      a0 += w * p[0]; a1 += w * p[128]; a2 += w * p[256]; a3 += w * p[384];
    }
    float bj = gcnb[j];
    aggs[bh * 4 + 0][j] = a0 + bj;
    aggs[bh * 4 + 1][j] = a1 + bj;
    aggs[bh * 4 + 2][j] = a2 + bj;
    aggs[bh * 4 + 3][j] = a3 + bj;
  }
  __syncthreads();
  // MLP: thread (b = tid>>5, t = tid&31) owns hidden dims {t, t+32}
  const int b = tid >> 5;
  const int t = tid & 31;
  float acc1 = b1[t], acc2 = b1[t + 32];
#pragma unroll 8
  for (int kc = 0; kc < 32; ++kc) {
    float4 a  = *(const float4*)&aggs[b][kc * 4];
    float4 w1 = *(const float4*)&W1T[t][kc * 4];
    float4 w2 = *(const float4*)&W1T[t + 32][kc * 4];
    acc1 += a.x * w1.x + a.y * w1.y + a.z * w1.z + a.w * w1.w;
    acc2 += a.x * w2.x + a.y * w2.y + a.z * w2.z + a.w * w2.w;
  }
  float s1 = acc1 * frcp(1.f + fexp2(-1.44269504f * acc1));
  float s2 = acc2 * frcp(1.f + fexp2(-1.44269504f * acc2));
  float part = s1 * W2[t] + s2 * W2[t + 32];
#pragma unroll
  for (int msk = 16; msk >= 1; msk >>= 1) part += __shfl_xor(part, msk);
  if (t == 0) out[(size_t)b * NN_ + d] = part + b2[0];
}

extern "C" void kernel_launch(void* const* d_in, const int* in_sizes, int n_in,
                              void* d_out, int out_size, void* d_ws, size_t ws_size,
                              hipStream_t stream) {
  const float* x    = (const float*)d_in[0];
  const int*   ei   = (const int*)d_in[1];
  const float* Wih  = (const float*)d_in[2];
  const float* Whh  = (const float*)d_in[3];
  const float* bih  = (const float*)d_in[4];
  const float* bhh  = (const float*)d_in[5];
  const float* gcnW = (const float*)d_in[6];
  const float* gcnb = (const float*)d_in[7];
  const float* W1   = (const float*)d_in[8];
  const float* b1   = (const float*)d_in[9];
  const float* W2   = (const float*)d_in[10];
  const float* b2   = (const float*)d_in[11];
  float* out = (float*)d_out;
  char* ws = (char*)d_ws;

  _Float16* W16    = (_Float16*)(ws);                    // 163840
  _Float16* Wg16   = (_Float16*)(ws + 163840);           // 32768
  float*    bias   = (float*)(ws + 196608);              // 2048
  float*    xwT    = (float*)(ws + 198656);              // 8192000  [node][batch][128]
  float*    deg    = (float*)(ws + 8390656);             // 8192
  float*    dinv   = (float*)(ws + 8398848);             // 8192
  int*      offs   = (int*)(ws + 8407040);               // 8192
  int*      cursor = (int*)(ws + 8415232);               // 8192
  int*      csrs   = (int*)(ws + 8423424);               // 128000
  float*    csrw   = (float*)(ws + 8551424);             // 128000

  prep_kernel<<<394, 256, 0, stream>>>(Wih, Whh, bih, bhh, gcnW, W16, Wg16, bias, deg);
  deg_kernel<<<133, 256, 0, stream>>>(ei, deg);
  scan_kernel<<<1, 1024, 0, stream>>>(deg, offs, cursor, dinv);
  fill_kernel<<<125, 256, 0, stream>>>(ei, dinv, cursor, csrs, csrw);
  lstm_gcn_kernel<<<500, 512, 0, stream>>>(x, W16, bias, Wg16, xwT);
  gathermlp_kernel<<<NN_, 256, 0, stream>>>(xwT, offs, deg, dinv, csrs, csrw,
                                            gcnb, W1, b1, W2, b2, out);
}